// Round 1
// baseline (534.119 us; speedup 1.0000x reference)
//
#include <hip/hip_runtime.h>
#include <hip/hip_bf16.h>

#define BS  4
#define SEQ 4096
#define DK  128

typedef __attribute__((ext_vector_type(8))) short bf16x8;
typedef __attribute__((ext_vector_type(4))) float f32x4;

// log2(e) / sqrt(128): p = exp(s_raw/sqrt(128)) = exp2(C1 * s_raw)
#define C1_SCALE (1.4426950408889634f / 11.313708498984761f)

__device__ inline unsigned pk_bf16(float a, float b) {
    __hip_bfloat162 h = __float22bfloat162_rn(make_float2(a, b));
    union { __hip_bfloat162 h2; unsigned u; } cv;
    cv.h2 = h;
    return cv.u;
}

__device__ inline bf16x8 pk8(float4 a, float4 b) {
    union { bf16x8 v; unsigned u[4]; } r;
    r.u[0] = pk_bf16(a.x, a.y);
    r.u[1] = pk_bf16(a.z, a.w);
    r.u[2] = pk_bf16(b.x, b.y);
    r.u[3] = pk_bf16(b.z, b.w);
    return r.v;
}

__device__ inline unsigned short bf16_1(float a) {
    __hip_bfloat16 h = __float2bfloat16(a);
    union { __hip_bfloat16 h1; unsigned short u; } cv;
    cv.h1 = h;
    return cv.u;
}

// ---------------------------------------------------------------------------
// Pass 1: l[b][k] = sum_q exp2(C1 * (Q[b,q,:] . K[b,k,:]))
// grid: (64 ktiles of 64 cols, 4 q-chunks of 1024, 4 batches), block 256.
// Each wave owns 16 k-columns; K B-frags are loop-invariant registers.
// ---------------------------------------------------------------------------
__global__ __launch_bounds__(256) void sdpa_pass1(
    const float* __restrict__ Q, const float* __restrict__ K,
    float* __restrict__ lsums)
{
    const int kt   = blockIdx.x;   // 0..63
    const int qc   = blockIdx.y;   // 0..3
    const int b    = blockIdx.z;   // 0..3
    const int w    = threadIdx.x >> 6;
    const int lane = threadIdx.x & 63;
    const int ln   = lane & 15;
    const int quad = lane >> 4;

    const int kcol = kt * 64 + w * 16 + ln;

    // B-operand frags for K rows (loop-invariant): B[kc][n], n=ln, kc=quad*8+j
    const float* kp = K + ((size_t)b * SEQ + kcol) * DK + quad * 8;
    bf16x8 kf[4];
#pragma unroll
    for (int c = 0; c < 4; ++c) {
        float4 a  = *(const float4*)(kp + c * 32);
        float4 bb = *(const float4*)(kp + c * 32 + 4);
        kf[c] = pk8(a, bb);
    }

    float lsum = 0.f;
    const float* qbase = Q + ((size_t)b * SEQ + qc * 1024 + ln) * DK + quad * 8;

    for (int st = 0; st < 64; ++st) {
        const float* qp = qbase + (size_t)st * 16 * DK;
        f32x4 s = {0.f, 0.f, 0.f, 0.f};
#pragma unroll
        for (int c = 0; c < 4; ++c) {
            float4 a  = *(const float4*)(qp + c * 32);
            float4 bb = *(const float4*)(qp + c * 32 + 4);
            bf16x8 qf = pk8(a, bb);
            s = __builtin_amdgcn_mfma_f32_16x16x32_bf16(qf, kf[c], s, 0, 0, 0);
        }
        // C layout: this lane's 4 regs are rows quad*4+r of column kcol
        lsum += __builtin_amdgcn_exp2f(C1_SCALE * s[0])
              + __builtin_amdgcn_exp2f(C1_SCALE * s[1])
              + __builtin_amdgcn_exp2f(C1_SCALE * s[2])
              + __builtin_amdgcn_exp2f(C1_SCALE * s[3]);
    }
    // combine the 4 quads that share column ln
    lsum += __shfl_xor(lsum, 16, 64);
    lsum += __shfl_xor(lsum, 32, 64);
    if (lane < 16)
        atomicAdd(&lsums[(size_t)b * SEQ + kcol], lsum);
}

// ---------------------------------------------------------------------------
// Pass 1b: winv = 1/l   (16384 elements)
// ---------------------------------------------------------------------------
__global__ __launch_bounds__(256) void sdpa_pass1b(
    const float* __restrict__ l, float* __restrict__ winv)
{
    int i = blockIdx.x * 256 + threadIdx.x;
    winv[i] = 1.0f / l[i];
}

// ---------------------------------------------------------------------------
// Pass 2: out[b,q,:] = sum_k exp2(C1*s_raw[q,k]) * winv[k] * V[k,:]
// grid: (128 q-tiles of 32, 4 batches), block 256 (4 waves).
// Wave (qs,h): QK for q-rows qs*16..+16, k-half h*32..+32 of a BK=64 tile;
//              PV for q-rows qs*16..+16, d-half h*64..+64.
// ---------------------------------------------------------------------------
__global__ __launch_bounds__(256) void sdpa_pass2(
    const float* __restrict__ Q, const float* __restrict__ K,
    const float* __restrict__ V, const float* __restrict__ winv,
    float* __restrict__ O)
{
    __shared__ unsigned short Kt[64][136];  // k-tile, row-major, bf16, pad 8
    __shared__ unsigned short Vt[128][72];  // V^T tile: [d][k], bf16, pad 8
    __shared__ unsigned short Pt[32][72];   // P tile: [q][k], bf16, pad 8

    const int qt   = blockIdx.x;   // 0..127
    const int b    = blockIdx.y;   // 0..3
    const int tid  = threadIdx.x;
    const int w    = tid >> 6;
    const int lane = tid & 63;
    const int ln   = lane & 15;
    const int quad = lane >> 4;
    const int qs   = w >> 1;       // q sub-tile (0/1)
    const int h    = w & 1;        // k-half for QK, d-half for PV

    // loop-invariant Q A-frags: A[m][kc], m=ln -> q row, kc=quad*8+j
    const int qrow = qt * 32 + qs * 16 + ln;
    const float* qp = Q + ((size_t)b * SEQ + qrow) * DK + quad * 8;
    bf16x8 qa[4];
#pragma unroll
    for (int c = 0; c < 4; ++c) {
        float4 a  = *(const float4*)(qp + c * 32);
        float4 bb = *(const float4*)(qp + c * 32 + 4);
        qa[c] = pk8(a, bb);
    }

    f32x4 acc[4];
#pragma unroll
    for (int c = 0; c < 4; ++c) acc[c] = (f32x4){0.f, 0.f, 0.f, 0.f};

    // staging roles
    const int krow_s = tid >> 2;   // 0..63  (K tile row)
    const int kseg   = tid & 3;    // 32-col segment
    const int vdb    = tid >> 3;   // 0..31 -> d = vdb*4
    const int vkb    = tid & 7;    // k rows vkb*8..+8

    for (int kt2 = 0; kt2 < 64; ++kt2) {
        const int k0 = kt2 * 64;

        // ---- stage K tile (64x128 fp32 -> bf16 LDS row-major) ----
        {
            const float* src = K + ((size_t)b * SEQ + k0 + krow_s) * DK + kseg * 32;
            unsigned short* dst = &Kt[krow_s][kseg * 32];
#pragma unroll
            for (int i = 0; i < 4; ++i) {
                float4 a  = *(const float4*)(src + i * 8);
                float4 bb = *(const float4*)(src + i * 8 + 4);
                *(bf16x8*)(dst + i * 8) = pk8(a, bb);
            }
        }
        // ---- stage V tile transposed, scaled by winv[k] ----
        {
            const float* wv = winv + (size_t)b * SEQ + k0 + vkb * 8;
            float4 w0 = *(const float4*)(wv);
            float4 w1 = *(const float4*)(wv + 4);
            float ws8[8] = {w0.x, w0.y, w0.z, w0.w, w1.x, w1.y, w1.z, w1.w};
            float vv[8][4];
#pragma unroll
            for (int kk = 0; kk < 8; ++kk) {
                float4 v4 = *(const float4*)(V + ((size_t)b * SEQ + k0 + vkb * 8 + kk) * DK + vdb * 4);
                vv[kk][0] = v4.x * ws8[kk];
                vv[kk][1] = v4.y * ws8[kk];
                vv[kk][2] = v4.z * ws8[kk];
                vv[kk][3] = v4.w * ws8[kk];
            }
#pragma unroll
            for (int dd = 0; dd < 4; ++dd) {
                union { bf16x8 v; unsigned u[4]; } r;
                r.u[0] = pk_bf16(vv[0][dd], vv[1][dd]);
                r.u[1] = pk_bf16(vv[2][dd], vv[3][dd]);
                r.u[2] = pk_bf16(vv[4][dd], vv[5][dd]);
                r.u[3] = pk_bf16(vv[6][dd], vv[7][dd]);
                *(bf16x8*)&Vt[vdb * 4 + dd][vkb * 8] = r.v;
            }
        }
        __syncthreads();

        // ---- QK -> P (each wave: 16 q x 32 k) ----
#pragma unroll
        for (int nn = 0; nn < 2; ++nn) {
            const int krow = h * 32 + nn * 16 + ln;   // B n-index = ln
            f32x4 s = {0.f, 0.f, 0.f, 0.f};
#pragma unroll
            for (int c = 0; c < 4; ++c) {
                bf16x8 kb = *(const bf16x8*)&Kt[krow][c * 32 + quad * 8];
                s = __builtin_amdgcn_mfma_f32_16x16x32_bf16(qa[c], kb, s, 0, 0, 0);
            }
#pragma unroll
            for (int r = 0; r < 4; ++r) {
                float p = __builtin_amdgcn_exp2f(C1_SCALE * s[r]);
                Pt[qs * 16 + quad * 4 + r][h * 32 + nn * 16 + ln] = bf16_1(p);
            }
        }
        __syncthreads();

        // ---- PV (each wave: 16 q x 64 d) ----
#pragma unroll
        for (int kc2 = 0; kc2 < 2; ++kc2) {
            bf16x8 pa = *(const bf16x8*)&Pt[qs * 16 + ln][kc2 * 32 + quad * 8];
#pragma unroll
            for (int c = 0; c < 4; ++c) {
                bf16x8 vb = *(const bf16x8*)&Vt[h * 64 + c * 16 + ln][kc2 * 32 + quad * 8];
                acc[c] = __builtin_amdgcn_mfma_f32_16x16x32_bf16(pa, vb, acc[c], 0, 0, 0);
            }
        }
        __syncthreads();
    }

    // ---- epilogue: C layout row = quad*4+r, col = ln ----
    float* ob = O + ((size_t)b * SEQ + qt * 32 + qs * 16 + quad * 4) * DK + h * 64 + ln;
#pragma unroll
    for (int c = 0; c < 4; ++c)
#pragma unroll
        for (int r = 0; r < 4; ++r)
            ob[(size_t)r * DK + c * 16] = acc[c][r];
}

extern "C" void kernel_launch(void* const* d_in, const int* in_sizes, int n_in,
                              void* d_out, int out_size, void* d_ws, size_t ws_size,
                              hipStream_t stream) {
    const float* q = (const float*)d_in[0];
    const float* k = (const float*)d_in[1];
    const float* v = (const float*)d_in[2];
    float* out = (float*)d_out;

    float* lsums = (float*)d_ws;             // BS*SEQ floats
    float* winv  = lsums + BS * SEQ;         // BS*SEQ floats

    hipMemsetAsync(lsums, 0, (size_t)BS * SEQ * sizeof(float), stream);
    sdpa_pass1 <<<dim3(64, 4, 4), 256, 0, stream>>>(q, k, lsums);
    sdpa_pass1b<<<dim3(BS * SEQ / 256), 256, 0, stream>>>(lsums, winv);
    sdpa_pass2 <<<dim3(SEQ / 32, BS), 256, 0, stream>>>(q, k, v, winv, out);
}

// Round 2
// 227.121 us; speedup vs baseline: 2.3517x; 2.3517x over previous
//
#include <hip/hip_runtime.h>
#include <hip/hip_bf16.h>

#define BS  4
#define SEQ 4096
#define DK  128

// p = exp(s_raw / sqrt(128)) = exp2(C1_SCALE * s_raw)
#define C1_SCALE (1.4426950408889634f / 11.313708498984761f)

typedef __attribute__((ext_vector_type(8))) short bf16x8;
typedef __attribute__((ext_vector_type(4))) float f32x4;
typedef unsigned short ushort_t;

__device__ inline unsigned pk_bf16(float a, float b) {
    __hip_bfloat162 h = __float22bfloat162_rn(make_float2(a, b));
    union { __hip_bfloat162 h2; unsigned u; } cv;
    cv.h2 = h;
    return cv.u;
}

__device__ inline bf16x8 pk8(float4 a, float4 b) {
    union { bf16x8 v; unsigned u[4]; } r;
    r.u[0] = pk_bf16(a.x, a.y);
    r.u[1] = pk_bf16(a.z, a.w);
    r.u[2] = pk_bf16(b.x, b.y);
    r.u[3] = pk_bf16(b.z, b.w);
    return r.v;
}

// ---------------------------------------------------------------------------
// Cast Q and K to bf16 (row-major, same layout).
// ---------------------------------------------------------------------------
__global__ __launch_bounds__(256) void cast_qk_kernel(
    const float* __restrict__ Q, const float* __restrict__ K,
    ushort_t* __restrict__ Qb, ushort_t* __restrict__ Kb)
{
    size_t i = ((size_t)blockIdx.x * 256 + threadIdx.x) * 8;
    float4 a = *(const float4*)(Q + i);
    float4 b = *(const float4*)(Q + i + 4);
    *(bf16x8*)(Qb + i) = pk8(a, b);
    a = *(const float4*)(K + i);
    b = *(const float4*)(K + i + 4);
    *(bf16x8*)(Kb + i) = pk8(a, b);
}

// ---------------------------------------------------------------------------
// Pass 1: lsums[b][k] = sum_q exp2(C1 * (Q[b,q,:] . K[b,k,:]))
// grid (kt=32, qs=4, b=4), 256 thr. K A-frags loop-invariant in regs,
// Q tile (32x128) staged in XOR-swizzled LDS. S^T orientation: A=K, B=Q.
// ---------------------------------------------------------------------------
__global__ __launch_bounds__(256) void sdpa_lsum(
    const ushort_t* __restrict__ Qb, const ushort_t* __restrict__ Kb,
    float* __restrict__ lsums)
{
    __shared__ ushort_t Qt[32 * 128];   // swizzled: 16 atoms (16B) per row

    const int kt = blockIdx.x;   // k-tile of 128 cols
    const int qs = blockIdx.y;   // q-chunk of 1024
    const int b  = blockIdx.z;
    const int tid = threadIdx.x;
    const int w = tid >> 6, lane = tid & 63, ln = lane & 15, quad = lane >> 4;

    // loop-invariant K A-frags: rows kt*128 + w*32 + mt*16 + ln
    bf16x8 ka[2][4];
#pragma unroll
    for (int mt = 0; mt < 2; ++mt)
#pragma unroll
        for (int c = 0; c < 4; ++c)
            ka[mt][c] = *(const bf16x8*)(Kb +
                ((size_t)(b * SEQ) + kt * 128 + w * 32 + mt * 16 + ln) * DK + c * 32 + quad * 8);

    float ls[2][4] = {};
    const int r_s = tid >> 3, sg = tid & 7;
    const ushort_t* qsrc = Qb + ((size_t)(b * SEQ) + qs * 1024 + r_s) * DK + sg * 16;

    for (int it = 0; it < 32; ++it) {
        uint4 q0 = *(const uint4*)(qsrc + (size_t)it * 32 * DK);
        uint4 q1 = *(const uint4*)(qsrc + (size_t)it * 32 * DK + 8);
        __syncthreads();
        *(uint4*)&Qt[r_s * 128 + (((2 * sg + 0) ^ (r_s & 15)) * 8)] = q0;
        *(uint4*)&Qt[r_s * 128 + (((2 * sg + 1) ^ (r_s & 15)) * 8)] = q1;
        __syncthreads();
#pragma unroll
        for (int nt = 0; nt < 2; ++nt) {
            bf16x8 qf[4];
#pragma unroll
            for (int c = 0; c < 4; ++c)
                qf[c] = *(const bf16x8*)&Qt[(nt * 16 + ln) * 128 + (((4 * c + quad) ^ ln) * 8)];
#pragma unroll
            for (int mt = 0; mt < 2; ++mt) {
                f32x4 s = {0.f, 0.f, 0.f, 0.f};
#pragma unroll
                for (int c = 0; c < 4; ++c)
                    s = __builtin_amdgcn_mfma_f32_16x16x32_bf16(ka[mt][c], qf[c], s, 0, 0, 0);
#pragma unroll
                for (int r = 0; r < 4; ++r)
                    ls[mt][r] += __builtin_amdgcn_exp2f(C1_SCALE * s[r]);
            }
        }
    }
    // sum over the 16 q-columns held across ln lanes (same quad group)
#pragma unroll
    for (int mt = 0; mt < 2; ++mt)
#pragma unroll
        for (int r = 0; r < 4; ++r) {
            float vv = ls[mt][r];
            vv += __shfl_xor(vv, 1);
            vv += __shfl_xor(vv, 2);
            vv += __shfl_xor(vv, 4);
            vv += __shfl_xor(vv, 8);
            ls[mt][r] = vv;
        }
    if (ln == 0) {
#pragma unroll
        for (int mt = 0; mt < 2; ++mt)
#pragma unroll
            for (int r = 0; r < 4; ++r)
                atomicAdd(&lsums[(size_t)b * SEQ + kt * 128 + w * 32 + mt * 16 + quad * 4 + r],
                          ls[mt][r]);
    }
}

// ---------------------------------------------------------------------------
// Build VbT[b][d][k] = bf16( V[b][k][d] / l[b][k] )  (scaled transpose)
// grid (kt=64, b=4), 256 thr, LDS-tiled transpose.
// ---------------------------------------------------------------------------
__global__ __launch_bounds__(256) void vb_transpose(
    const float* __restrict__ V, const float* __restrict__ lsums,
    ushort_t* __restrict__ VbT)
{
    __shared__ float Vl[64][132];
    __shared__ float Wl[64];

    const int kt = blockIdx.x;
    const int b  = blockIdx.y;
    const int tid = threadIdx.x;
    const int k0 = kt * 64;
    {
        int r = tid >> 2, sg = tid & 3;
        const float* src = V + ((size_t)(b * SEQ) + k0 + r) * DK + sg * 32;
#pragma unroll
        for (int i = 0; i < 8; ++i)
            *(float4*)&Vl[r][sg * 32 + i * 4] = *(const float4*)(src + i * 4);
    }
    if (tid < 64) Wl[tid] = 1.0f / lsums[(size_t)b * SEQ + k0 + tid];
    __syncthreads();

    const int d = tid >> 1, kh = tid & 1;
    unsigned u[16];
#pragma unroll
    for (int j = 0; j < 16; ++j) {
        int row = kh * 32 + j * 2;
        float v0 = Vl[row][d]     * Wl[row];
        float v1 = Vl[row + 1][d] * Wl[row + 1];
        u[j] = pk_bf16(v0, v1);
    }
    ushort_t* dst = VbT + ((size_t)(b * DK) + d) * SEQ + k0 + kh * 32;
#pragma unroll
    for (int i = 0; i < 4; ++i) {
        uint4 t4; t4.x = u[i*4]; t4.y = u[i*4+1]; t4.z = u[i*4+2]; t4.w = u[i*4+3];
        *(uint4*)(dst + i * 8) = t4;
    }
}

// ---------------------------------------------------------------------------
// Pass 2: O[b,q,:] += sum_k exp2(C1*s) * V'[k,:]   (V' pre-scaled by 1/l)
// grid (qt=64, ks=2, b=4), 256 thr (4 waves). Tile 64q x 128d, BK=64,
// k-split 2 with fp32 atomicAdd epilogue. Software-pipelined staging
// (global->reg prefetch, reg->LDS commit), Vt double-buffered, 2 barriers/iter.
// XOR-swizzled LDS. QK uses S^T orientation so P lands as ds_write_b64
// directly in PV's A-operand layout.
// ---------------------------------------------------------------------------
__global__ __launch_bounds__(256) void sdpa_out(
    const ushort_t* __restrict__ Qb, const ushort_t* __restrict__ Kb,
    const ushort_t* __restrict__ VbT, float* __restrict__ O)
{
    __shared__ ushort_t Kt[64 * 128];      // 16 KB, swizzle mask 15
    __shared__ ushort_t Vt[2][128 * 64];   // 2 x 16 KB, swizzle mask 7
    __shared__ ushort_t Pt[64 * 64];       // 8 KB, swizzle mask 7

    const int qt = blockIdx.x;   // 0..63
    const int ks = blockIdx.y;   // 0..1 (k-split)
    const int b  = blockIdx.z;
    const int tid = threadIdx.x;
    const int w = tid >> 6, lane = tid & 63, ln = lane & 15, quad = lane >> 4;

    // loop-invariant Q frags (B-operand of S^T): q rows qt*64 + w*16 + ln
    bf16x8 qa[4];
#pragma unroll
    for (int c = 0; c < 4; ++c)
        qa[c] = *(const bf16x8*)(Qb +
            ((size_t)(b * SEQ) + qt * 64 + w * 16 + ln) * DK + c * 32 + quad * 8);

    f32x4 acc[8];
#pragma unroll
    for (int i = 0; i < 8; ++i) acc[i] = (f32x4){0.f, 0.f, 0.f, 0.f};

    const int kr = tid >> 2, ksg = tid & 3;   // K staging: row, 32-col seg
    const int vd = tid >> 1, vh = tid & 1;    // V staging: d-row, 32-k seg
    const ushort_t* Ksrc = Kb  + ((size_t)(b * SEQ) + ks * 2048 + kr) * DK + ksg * 32;
    const ushort_t* Vsrc = VbT + ((size_t)(b * DK) + vd) * SEQ + ks * 2048 + vh * 32;

    uint4 kreg[4], vreg[4];
#pragma unroll
    for (int i = 0; i < 4; ++i) {
        kreg[i] = *(const uint4*)(Ksrc + i * 8);
        vreg[i] = *(const uint4*)(Vsrc + i * 8);
    }

    int p = 0;
    for (int kt2 = 0; kt2 < 32; ++kt2) {
        // commit staged regs to LDS (Kt single-buffered, Vt double-buffered)
#pragma unroll
        for (int i = 0; i < 4; ++i) {
            *(uint4*)&Kt[kr * 128 + (((ksg * 4 + i) ^ (kr & 15)) * 8)] = kreg[i];
            *(uint4*)&Vt[p][vd * 64 + (((vh * 4 + i) ^ (vd & 7)) * 8)] = vreg[i];
        }
        __syncthreads();
        if (kt2 < 31) {  // prefetch next tile into regs; lands during compute
#pragma unroll
            for (int i = 0; i < 4; ++i) {
                kreg[i] = *(const uint4*)(Ksrc + (size_t)(kt2 + 1) * 64 * DK + i * 8);
                vreg[i] = *(const uint4*)(Vsrc + (kt2 + 1) * 64 + i * 8);
            }
        }
        // ---- QK (S^T): A = K rows, B = Q; C col=q=ln, row=k=quad*4+r ----
#pragma unroll
        for (int mt = 0; mt < 4; ++mt) {
            f32x4 s = {0.f, 0.f, 0.f, 0.f};
#pragma unroll
            for (int c = 0; c < 4; ++c) {
                bf16x8 kf = *(const bf16x8*)&Kt[(mt * 16 + ln) * 128 + (((4 * c + quad) ^ ln) * 8)];
                s = __builtin_amdgcn_mfma_f32_16x16x32_bf16(kf, qa[c], s, 0, 0, 0);
            }
            uint2 pw;
            pw.x = pk_bf16(__builtin_amdgcn_exp2f(C1_SCALE * s[0]),
                           __builtin_amdgcn_exp2f(C1_SCALE * s[1]));
            pw.y = pk_bf16(__builtin_amdgcn_exp2f(C1_SCALE * s[2]),
                           __builtin_amdgcn_exp2f(C1_SCALE * s[3]));
            *(uint2*)&Pt[(w * 16 + ln) * 64 +
                         (((2 * mt + (quad >> 1)) ^ (ln & 7)) * 8) + (quad & 1) * 4] = pw;
        }
        __syncthreads();
        // ---- PV: A = P (this wave's 16 q), B = V^T ----
#pragma unroll
        for (int kc = 0; kc < 2; ++kc) {
            bf16x8 pa = *(const bf16x8*)&Pt[(w * 16 + ln) * 64 + (((4 * kc + quad) ^ (ln & 7)) * 8)];
#pragma unroll
            for (int dt = 0; dt < 8; ++dt) {
                bf16x8 vf = *(const bf16x8*)&Vt[p][(dt * 16 + ln) * 64 + (((4 * kc + quad) ^ (ln & 7)) * 8)];
                acc[dt] = __builtin_amdgcn_mfma_f32_16x16x32_bf16(pa, vf, acc[dt], 0, 0, 0);
            }
        }
        p ^= 1;
    }

    // epilogue: k-split partial sums -> atomicAdd (O zeroed by launcher)
    float* ob = O + ((size_t)(b * SEQ) + qt * 64 + w * 16 + quad * 4) * DK;
#pragma unroll
    for (int dt = 0; dt < 8; ++dt)
#pragma unroll
        for (int r = 0; r < 4; ++r)
            atomicAdd(&ob[(size_t)r * DK + dt * 16 + ln], acc[dt][r]);
}

extern "C" void kernel_launch(void* const* d_in, const int* in_sizes, int n_in,
                              void* d_out, int out_size, void* d_ws, size_t ws_size,
                              hipStream_t stream) {
    const float* q = (const float*)d_in[0];
    const float* k = (const float*)d_in[1];
    const float* v = (const float*)d_in[2];
    float* out = (float*)d_out;

    float*    lsums = (float*)d_ws;                                  // 64 KB
    ushort_t* Qb    = (ushort_t*)((char*)d_ws + 65536);              // 4 MB
    ushort_t* Kb    = Qb + (size_t)BS * SEQ * DK;                    // 4 MB
    ushort_t* VbT   = Kb + (size_t)BS * SEQ * DK;                    // 4 MB

    hipMemsetAsync(lsums, 0, (size_t)BS * SEQ * sizeof(float), stream);
    hipMemsetAsync(out, 0, (size_t)BS * SEQ * DK * sizeof(float), stream);

    cast_qk_kernel<<<dim3(BS * SEQ * DK / 8 / 256), 256, 0, stream>>>(q, k, Qb, Kb);
    sdpa_lsum     <<<dim3(32, 4, 4),  256, 0, stream>>>(Qb, Kb, lsums);
    vb_transpose  <<<dim3(64, 4),     256, 0, stream>>>(v, lsums, VbT);
    sdpa_out      <<<dim3(64, 2, 4),  256, 0, stream>>>(Qb, Kb, VbT, out);
}

// Round 3
// 226.642 us; speedup vs baseline: 2.3567x; 1.0021x over previous
//
#include <hip/hip_runtime.h>
#include <hip/hip_bf16.h>

#define BS  4
#define SEQ 4096
#define DK  128

// p = exp(s_raw / sqrt(128)) = exp2(C1_SCALE * s_raw)
#define C1_SCALE (1.4426950408889634f / 11.313708498984761f)

typedef __attribute__((ext_vector_type(8))) short bf16x8;
typedef __attribute__((ext_vector_type(4))) float f32x4;
typedef unsigned short ushort_t;

__device__ inline unsigned pk_bf16(float a, float b) {
    __hip_bfloat162 h = __float22bfloat162_rn(make_float2(a, b));
    union { __hip_bfloat162 h2; unsigned u; } cv;
    cv.h2 = h;
    return cv.u;
}

__device__ inline bf16x8 pk8(float4 a, float4 b) {
    union { bf16x8 v; unsigned u[4]; } r;
    r.u[0] = pk_bf16(a.x, a.y);
    r.u[1] = pk_bf16(a.z, a.w);
    r.u[2] = pk_bf16(b.x, b.y);
    r.u[3] = pk_bf16(b.z, b.w);
    return r.v;
}

// async global->LDS, 16B per lane; lds base must be wave-uniform
__device__ inline void gld_lds16(const ushort_t* g, ushort_t* l) {
    __builtin_amdgcn_global_load_lds(
        (const __attribute__((address_space(1))) unsigned int*)g,
        (__attribute__((address_space(3))) unsigned int*)l,
        16, 0, 0);
}

// ---------------------------------------------------------------------------
// Swizzled layouts (atom = 16 B = 8 bf16):
//   Qb/Kb: row r (global, 16 atoms/row): atom a stored at r*16 + (a ^ (r&15))
//   VbT:   per (b, kt) tile (128 d x 64 k): atom(d, a=k/8) at d*8 + (a ^ (d&7))
// So a linear lane->atom DMA of a 64-row K tile / 32-row Q tile / V tile
// reproduces exactly the swizzled LDS image the MFMA fragment reads expect.
// ---------------------------------------------------------------------------

__global__ __launch_bounds__(256) void cast_qk_sw(
    const float* __restrict__ Q, const float* __restrict__ K,
    ushort_t* __restrict__ Qb, ushort_t* __restrict__ Kb)
{
    const int g = blockIdx.x * 256 + threadIdx.x;   // atom id 0..262143
    const int q = g >> 4, ap = g & 15;
    const int a = ap ^ (q & 15);
    const float* src = Q + (size_t)q * DK + a * 8;
    float4 x = *(const float4*)src, y = *(const float4*)(src + 4);
    *(bf16x8*)(Qb + (size_t)g * 8) = pk8(x, y);
    src = K + (size_t)q * DK + a * 8;
    x = *(const float4*)src; y = *(const float4*)(src + 4);
    *(bf16x8*)(Kb + (size_t)g * 8) = pk8(x, y);
}

// ---------------------------------------------------------------------------
// lsums[b][k] = sum_q exp2(C1 * (Q[q,:] . K[k,:]))
// grid (kt=16, qs=16, b=4) = 1024 blocks, 4 waves. Wave owns 64 k rows in
// regs (A-operand); Q tiles (32x128) DMA'd into double-buffered LDS,
// ONE barrier per iter.
// ---------------------------------------------------------------------------
__global__ __launch_bounds__(256, 4) void sdpa_lsum(
    const ushort_t* __restrict__ Qb, const ushort_t* __restrict__ Kb,
    float* __restrict__ lsums)
{
    __shared__ ushort_t Qt[2][32 * 128];

    const int kt = blockIdx.x, qs = blockIdx.y, b = blockIdx.z;
    const int tid = threadIdx.x;
    const int w = tid >> 6, lane = tid & 63, ln = lane & 15, quad = lane >> 4;

    bf16x8 ka[4][4];   // [mt][c] : k rows kt*256 + w*64 + mt*16 + ln
#pragma unroll
    for (int mt = 0; mt < 4; ++mt)
#pragma unroll
        for (int c = 0; c < 4; ++c) {
            int krow = b * SEQ + kt * 256 + w * 64 + mt * 16 + ln;
            ka[mt][c] = *(const bf16x8*)(Kb + (size_t)krow * 128 +
                                         (((c * 4 + quad) ^ ln) * 8));
        }

    float ls[4][4];
#pragma unroll
    for (int mt = 0; mt < 4; ++mt)
#pragma unroll
        for (int r = 0; r < 4; ++r) ls[mt][r] = 0.f;

    const size_t qtile0 = ((size_t)(b * SEQ + qs * 256)) * 128;
#pragma unroll
    for (int j = 0; j < 2; ++j)
        gld_lds16(Qb + qtile0 + (j * 256 + tid) * 8,
                  &Qt[0][(j * 256 + w * 64) * 8]);

    for (int it = 0; it < 8; ++it) {
        __syncthreads();   // drains DMA(it); all waves done with buf[(it+1)&1]
        if (it < 7) {
            const size_t nb = qtile0 + (size_t)(it + 1) * 32 * 128;
#pragma unroll
            for (int j = 0; j < 2; ++j)
                gld_lds16(Qb + nb + (j * 256 + tid) * 8,
                          &Qt[(it + 1) & 1][(j * 256 + w * 64) * 8]);
        }
        const ushort_t* qt = Qt[it & 1];
        bf16x8 qf[2][4];
#pragma unroll
        for (int nt = 0; nt < 2; ++nt)
#pragma unroll
            for (int c = 0; c < 4; ++c)
                qf[nt][c] = *(const bf16x8*)&qt[((nt * 16 + ln) * 16 +
                                                (((c * 4 + quad) ^ ln))) * 8];
#pragma unroll
        for (int mt = 0; mt < 4; ++mt)
#pragma unroll
            for (int nt = 0; nt < 2; ++nt) {
                f32x4 s = {0.f, 0.f, 0.f, 0.f};
#pragma unroll
                for (int c = 0; c < 4; ++c)
                    s = __builtin_amdgcn_mfma_f32_16x16x32_bf16(ka[mt][c], qf[nt][c], s, 0, 0, 0);
#pragma unroll
                for (int r = 0; r < 4; ++r)
                    ls[mt][r] += __builtin_amdgcn_exp2f(C1_SCALE * s[r]);
            }
    }
    // lanes ln hold distinct q; reduce over ln, result per k row
#pragma unroll
    for (int mt = 0; mt < 4; ++mt)
#pragma unroll
        for (int r = 0; r < 4; ++r) {
            float vv = ls[mt][r];
            vv += __shfl_xor(vv, 1);
            vv += __shfl_xor(vv, 2);
            vv += __shfl_xor(vv, 4);
            vv += __shfl_xor(vv, 8);
            ls[mt][r] = vv;
        }
    if (ln == 0) {
#pragma unroll
        for (int mt = 0; mt < 4; ++mt)
#pragma unroll
            for (int r = 0; r < 4; ++r)
                atomicAdd(&lsums[(size_t)b * SEQ + kt * 256 + w * 64 + mt * 16 + quad * 4 + r],
                          ls[mt][r]);
    }
}

// ---------------------------------------------------------------------------
// VbT tile (b,kt): bf16( V[k][d] / l[k] ), transposed to [d][k], swizzled.
// ---------------------------------------------------------------------------
__global__ __launch_bounds__(256) void vb_transpose(
    const float* __restrict__ V, const float* __restrict__ lsums,
    ushort_t* __restrict__ VbT)
{
    __shared__ float Vl[64][132];
    __shared__ float Wl[64];

    const int kt = blockIdx.x, b = blockIdx.y;
    const int tid = threadIdx.x;
    const int k0 = kt * 64;
    {
        int r = tid >> 2, sg = tid & 3;
        const float* src = V + ((size_t)(b * SEQ) + k0 + r) * DK + sg * 32;
#pragma unroll
        for (int i = 0; i < 8; ++i)
            *(float4*)&Vl[r][sg * 32 + i * 4] = *(const float4*)(src + i * 4);
    }
    if (tid < 64) Wl[tid] = 1.0f / lsums[(size_t)b * SEQ + k0 + tid];
    __syncthreads();

    const int d = tid >> 1, kh = tid & 1;
    unsigned u[16];
#pragma unroll
    for (int j = 0; j < 16; ++j) {
        int row = kh * 32 + j * 2;
        u[j] = pk_bf16(Vl[row][d] * Wl[row], Vl[row + 1][d] * Wl[row + 1]);
    }
    ushort_t* base = VbT + ((size_t)(b * 64 + kt)) * 8192;
#pragma unroll
    for (int i = 0; i < 4; ++i) {
        uint4 t4; t4.x = u[i*4]; t4.y = u[i*4+1]; t4.z = u[i*4+2]; t4.w = u[i*4+3];
        int a = kh * 4 + i;
        *(uint4*)(base + (d * 8 + (a ^ (d & 7))) * 8) = t4;
    }
}

// ---------------------------------------------------------------------------
// O[b,q,:] += sum_k exp2(C1*s) * V'[k,:]
// grid (qt=64, ks=4, b=4) = 1024 blocks (4/CU), 4 waves, 40 KB LDS.
// Per iter (BK=64): DMA-staged Kt/Vt, wave owns k-slice for QK (A=Kt 4 reads,
// B=Q in 64 regs) and d-slice for PV. 3 barriers/iter; K-DMA covered by PV.
// ---------------------------------------------------------------------------
__global__ __launch_bounds__(256, 4) void sdpa_out(
    const ushort_t* __restrict__ Qb, const ushort_t* __restrict__ Kb,
    const ushort_t* __restrict__ VbT, float* __restrict__ O)
{
    __shared__ ushort_t Kt[64 * 128];   // atom(r,a) at r*16 + (a^(r&15))
    __shared__ ushort_t Vt[128 * 64];   // atom(d,a) at d*8  + (a^(d&7))
    __shared__ ushort_t Pt[64 * 64];    // atom16(q,a) at q*8 + (a^(q&7))

    const int qt = blockIdx.x, ks = blockIdx.y, b = blockIdx.z;
    const int tid = threadIdx.x;
    const int w = tid >> 6, lane = tid & 63, ln = lane & 15, quad = lane >> 4;

    // loop-invariant Q B-frags covering all 64 q of the block
    bf16x8 qa[4][4];   // [c][nt]
#pragma unroll
    for (int nt = 0; nt < 4; ++nt)
#pragma unroll
        for (int c = 0; c < 4; ++c) {
            int qrow = b * SEQ + qt * 64 + nt * 16 + ln;
            qa[c][nt] = *(const bf16x8*)(Qb + (size_t)qrow * 128 +
                                         (((c * 4 + quad) ^ ln) * 8));
        }

    f32x4 acc[4][2];
#pragma unroll
    for (int i = 0; i < 4; ++i)
#pragma unroll
        for (int j = 0; j < 2; ++j) acc[i][j] = (f32x4){0.f, 0.f, 0.f, 0.f};

    const size_t kbase = ((size_t)(b * SEQ + ks * 1024)) * 128;
    const size_t vbase = ((size_t)(b * 64 + ks * 16)) * 8192;

#pragma unroll
    for (int j = 0; j < 4; ++j) {
        gld_lds16(Kb  + kbase + (j * 256 + tid) * 8, &Kt[(j * 256 + w * 64) * 8]);
        gld_lds16(VbT + vbase + (j * 256 + tid) * 8, &Vt[(j * 256 + w * 64) * 8]);
    }

    for (int i = 0; i < 16; ++i) {
        __syncthreads();   // sync_a: DMA(i) drained; Pt free (PV(i-1) done)

        // ---- QK: A = Kt k-slice (w*16..+16), B = qa; S^T C layout ----
        bf16x8 kf[4];
#pragma unroll
        for (int c = 0; c < 4; ++c)
            kf[c] = *(const bf16x8*)&Kt[((w * 16 + ln) * 16 + ((c * 4 + quad) ^ ln)) * 8];
#pragma unroll
        for (int nt = 0; nt < 4; ++nt) {
            f32x4 s = {0.f, 0.f, 0.f, 0.f};
#pragma unroll
            for (int c = 0; c < 4; ++c)
                s = __builtin_amdgcn_mfma_f32_16x16x32_bf16(kf[c], qa[c][nt], s, 0, 0, 0);
            // q = nt*16+ln (col), k = w*16 + quad*4 + r (row)
            uint2 pw;
            pw.x = pk_bf16(__builtin_amdgcn_exp2f(C1_SCALE * s[0]),
                           __builtin_amdgcn_exp2f(C1_SCALE * s[1]));
            pw.y = pk_bf16(__builtin_amdgcn_exp2f(C1_SCALE * s[2]),
                           __builtin_amdgcn_exp2f(C1_SCALE * s[3]));
            const int q = nt * 16 + ln;
            const int a16 = w * 2 + (quad >> 1);
            *(uint2*)&Pt[q * 64 + ((a16 ^ (q & 7)) * 8) + (quad & 1) * 4] = pw;
        }
        __syncthreads();   // sync_b: Pt visible, Kt free

        if (i < 15) {      // K-DMA(i+1), covered by PV compute
            const size_t kb2 = kbase + (size_t)(i + 1) * 64 * 128;
#pragma unroll
            for (int j = 0; j < 4; ++j)
                gld_lds16(Kb + kb2 + (j * 256 + tid) * 8, &Kt[(j * 256 + w * 64) * 8]);
        }

        // ---- PV: A = Pt (all 64 q), B = Vt d-slice (w*32..+32) ----
#pragma unroll
        for (int kc = 0; kc < 2; ++kc) {
            bf16x8 vf[2], pa[4];
#pragma unroll
            for (int dt = 0; dt < 2; ++dt)
                vf[dt] = *(const bf16x8*)&Vt[((w * 32 + dt * 16 + ln) * 8 +
                                             ((kc * 4 + quad) ^ (ln & 7))) * 8];
#pragma unroll
            for (int qf2 = 0; qf2 < 4; ++qf2)
                pa[qf2] = *(const bf16x8*)&Pt[(qf2 * 16 + ln) * 64 +
                                              (((kc * 4 + quad) ^ (ln & 7)) * 8)];
#pragma unroll
            for (int qf2 = 0; qf2 < 4; ++qf2)
#pragma unroll
                for (int dt = 0; dt < 2; ++dt)
                    acc[qf2][dt] = __builtin_amdgcn_mfma_f32_16x16x32_bf16(
                        pa[qf2], vf[dt], acc[qf2][dt], 0, 0, 0);
        }
        __syncthreads();   // sync_c: Vt free

        if (i < 15) {      // V-DMA(i+1)
            const size_t vb2 = vbase + (size_t)(i + 1) * 8192;
#pragma unroll
            for (int j = 0; j < 4; ++j)
                gld_lds16(VbT + vb2 + (j * 256 + tid) * 8, &Vt[(j * 256 + w * 64) * 8]);
        }
    }

    // epilogue: k-split partials via atomics (O zeroed by launcher)
#pragma unroll
    for (int qf2 = 0; qf2 < 4; ++qf2)
#pragma unroll
        for (int dt = 0; dt < 2; ++dt)
#pragma unroll
            for (int r = 0; r < 4; ++r)
                atomicAdd(&O[((size_t)(b * SEQ) + qt * 64 + qf2 * 16 + quad * 4 + r) * DK +
                             w * 32 + dt * 16 + ln], acc[qf2][dt][r]);
}

extern "C" void kernel_launch(void* const* d_in, const int* in_sizes, int n_in,
                              void* d_out, int out_size, void* d_ws, size_t ws_size,
                              hipStream_t stream) {
    const float* q = (const float*)d_in[0];
    const float* k = (const float*)d_in[1];
    const float* v = (const float*)d_in[2];
    float* out = (float*)d_out;

    float*    lsums = (float*)d_ws;                         // 64 KB
    ushort_t* Qb    = (ushort_t*)((char*)d_ws + 65536);     // 4 MB
    ushort_t* Kb    = Qb + (size_t)BS * SEQ * DK;           // 4 MB
    ushort_t* VbT   = Kb + (size_t)BS * SEQ * DK;           // 4 MB

    hipMemsetAsync(lsums, 0, (size_t)BS * SEQ * sizeof(float), stream);
    hipMemsetAsync(out, 0, (size_t)BS * SEQ * DK * sizeof(float), stream);

    cast_qk_sw  <<<dim3(BS * SEQ * 16 / 256), 256, 0, stream>>>(q, k, Qb, Kb);
    sdpa_lsum   <<<dim3(16, 16, 4), 256, 0, stream>>>(Qb, Kb, lsums);
    vb_transpose<<<dim3(64, 4),     256, 0, stream>>>(v, lsums, VbT);
    sdpa_out    <<<dim3(64, 4, 4),  256, 0, stream>>>(Qb, Kb, VbT, out);
}